// Round 1
// baseline (3559.406 us; speedup 1.0000x reference)
//
#include <hip/hip_runtime.h>
#include <math.h>

// Problem constants
constexpr int B_ = 4, S_ = 2048, IND = 1024, MD = 1024, H_ = 16, D_ = 64;
constexpr int MROWS = B_ * S_;          // 8192 rows of the flat [B*S, M] matrices
constexpr int NHEAD = B_ * H_;          // 64 "heads" (contiguous slabs, faithful reshape)
constexpr int SP = 2048;                // rows per head after .view(B*H, -1, D)
constexpr long OUT_ELEMS = (long)MROWS * MD;        // 8,388,608
constexpr long ATTN_ELEMS = (long)NHEAD * SP * SP;  // 268,435,456

// ---------------------------------------------------------------------------
// GEMM: C[M,N] = A[M,K] @ W[K,N] + bias[N]   (fp32, 128x128 tile, BK=8, 8x8/thread)
// ---------------------------------------------------------------------------
__global__ __launch_bounds__(256) void gemm_bias_128(
    const float* __restrict__ A, const float* __restrict__ W,
    const float* __restrict__ bias, float* __restrict__ C,
    int M, int N, int K)
{
    __shared__ __align__(16) float As[8][128];
    __shared__ __align__(16) float Ws[8][128];
    const int t  = threadIdx.x;
    const int tx = t & 15, ty = t >> 4;
    const int bn = blockIdx.x * 128, bm = blockIdx.y * 128;

    const int arow = t >> 1, acol = (t & 1) << 2;   // A tile: 128 rows x 8 cols
    const int wrow = t >> 5, wcol = (t & 31) << 2;  // W tile: 8 rows x 128 cols

    float acc[8][8] = {};

    const float* Aptr = A + (long)(bm + arow) * K + acol;
    const float* Wptr = W + (long)wrow * N + bn + wcol;

    for (int k0 = 0; k0 < K; k0 += 8) {
        float4 av = *(const float4*)(Aptr + k0);
        float4 wv = *(const float4*)(Wptr + (long)k0 * N);
        __syncthreads();   // protect LDS from previous iteration's readers
        As[acol + 0][arow] = av.x;
        As[acol + 1][arow] = av.y;
        As[acol + 2][arow] = av.z;
        As[acol + 3][arow] = av.w;
        *(float4*)&Ws[wrow][wcol] = wv;
        __syncthreads();
#pragma unroll
        for (int k = 0; k < 8; ++k) {
            float a[8], b[8];
            *(float4*)(a)     = *(const float4*)&As[k][ty * 8];
            *(float4*)(a + 4) = *(const float4*)&As[k][ty * 8 + 4];
            *(float4*)(b)     = *(const float4*)&Ws[k][tx * 8];
            *(float4*)(b + 4) = *(const float4*)&Ws[k][tx * 8 + 4];
#pragma unroll
            for (int i = 0; i < 8; ++i)
#pragma unroll
                for (int j = 0; j < 8; ++j)
                    acc[i][j] += a[i] * b[j];
        }
    }

#pragma unroll
    for (int i = 0; i < 8; ++i) {
        const int row = bm + ty * 8 + i;
#pragma unroll
        for (int j4 = 0; j4 < 2; ++j4) {
            const int col = bn + tx * 8 + j4 * 4;
            float4 bv = *(const float4*)&bias[col];
            float4 o;
            o.x = acc[i][j4 * 4 + 0] + bv.x;
            o.y = acc[i][j4 * 4 + 1] + bv.y;
            o.z = acc[i][j4 * 4 + 2] + bv.z;
            o.w = acc[i][j4 * 4 + 3] + bv.w;
            *(float4*)&C[(long)row * N + col] = o;
        }
    }
}

// ---------------------------------------------------------------------------
// Scores: per head, S = Qh @ Kh^T * scale.  Qh,Kh are contiguous [2048,64].
// Raw (pre-softmax) scores written straight into d_out's attn region.
// ---------------------------------------------------------------------------
__global__ __launch_bounds__(256) void scores_kernel(
    const float* __restrict__ QH, const float* __restrict__ KH,
    float* __restrict__ attn, float scale)
{
    __shared__ __align__(16) float Qs[64][64];  // [k][m] (transposed)
    __shared__ __align__(16) float Ks[64][64];  // [k][n] (transposed)
    const int t  = threadIdx.x;
    const int tx = t & 15, ty = t >> 4;
    const int head = blockIdx.z;
    const int i0 = blockIdx.y * 64, j0 = blockIdx.x * 64;

    const float* Qbase = QH + (long)head * SP * 64;
    const float* Kbase = KH + (long)head * SP * 64;

#pragma unroll
    for (int it = 0; it < 4; ++it) {
        const int idx = t + it * 256;            // 0..1023 float4s
        const int r = idx >> 4, c4 = (idx & 15) << 2;
        float4 qv = *(const float4*)(Qbase + (long)(i0 + r) * 64 + c4);
        Qs[c4 + 0][r] = qv.x; Qs[c4 + 1][r] = qv.y;
        Qs[c4 + 2][r] = qv.z; Qs[c4 + 3][r] = qv.w;
        float4 kv = *(const float4*)(Kbase + (long)(j0 + r) * 64 + c4);
        Ks[c4 + 0][r] = kv.x; Ks[c4 + 1][r] = kv.y;
        Ks[c4 + 2][r] = kv.z; Ks[c4 + 3][r] = kv.w;
    }
    __syncthreads();

    float acc[4][4] = {};
#pragma unroll
    for (int k = 0; k < 64; ++k) {
        float a[4], b[4];
        *(float4*)a = *(const float4*)&Qs[k][ty * 4];
        *(float4*)b = *(const float4*)&Ks[k][tx * 4];
#pragma unroll
        for (int i = 0; i < 4; ++i)
#pragma unroll
            for (int j = 0; j < 4; ++j)
                acc[i][j] += a[i] * b[j];
    }

    float* out = attn + (long)head * SP * SP;
#pragma unroll
    for (int i = 0; i < 4; ++i) {
        float4 o;
        o.x = acc[i][0] * scale; o.y = acc[i][1] * scale;
        o.z = acc[i][2] * scale; o.w = acc[i][3] * scale;
        *(float4*)&out[(long)(i0 + ty * 4 + i) * SP + j0 + tx * 4] = o;
    }
}

// ---------------------------------------------------------------------------
// Row softmax in place over attn rows (length 2048). One block per row.
// ---------------------------------------------------------------------------
__global__ __launch_bounds__(256) void softmax_kernel(float* __restrict__ attn)
{
    __shared__ float red[256];
    const long row = blockIdx.x;
    float4* p = (float4*)(attn + row * (long)SP);
    const int t = threadIdx.x;

    float4 v0 = p[t];
    float4 v1 = p[t + 256];
    float m = fmaxf(fmaxf(fmaxf(v0.x, v0.y), fmaxf(v0.z, v0.w)),
                    fmaxf(fmaxf(v1.x, v1.y), fmaxf(v1.z, v1.w)));
    red[t] = m; __syncthreads();
    for (int s = 128; s > 0; s >>= 1) {
        if (t < s) red[t] = fmaxf(red[t], red[t + s]);
        __syncthreads();
    }
    m = red[0]; __syncthreads();

    v0.x = __expf(v0.x - m); v0.y = __expf(v0.y - m);
    v0.z = __expf(v0.z - m); v0.w = __expf(v0.w - m);
    v1.x = __expf(v1.x - m); v1.y = __expf(v1.y - m);
    v1.z = __expf(v1.z - m); v1.w = __expf(v1.w - m);
    float s8 = v0.x + v0.y + v0.z + v0.w + v1.x + v1.y + v1.z + v1.w;
    red[t] = s8; __syncthreads();
    for (int s = 128; s > 0; s >>= 1) {
        if (t < s) red[t] += red[t + s];
        __syncthreads();
    }
    const float inv = 1.0f / red[0];

    v0.x *= inv; v0.y *= inv; v0.z *= inv; v0.w *= inv;
    v1.x *= inv; v1.y *= inv; v1.z *= inv; v1.w *= inv;
    p[t] = v0; p[t + 256] = v1;
}

// ---------------------------------------------------------------------------
// PV: per head, CTX[2048,64] = attn[2048,2048] @ Vh[2048,64]
// ---------------------------------------------------------------------------
__global__ __launch_bounds__(256) void pv_kernel(
    const float* __restrict__ attn, const float* __restrict__ VH,
    float* __restrict__ CTX)
{
    __shared__ __align__(16) float As[32][64];  // [k][m] (transposed attn tile)
    __shared__ __align__(16) float Vs[32][64];  // [k][n] (natural V layout)
    const int t  = threadIdx.x;
    const int tx = t & 15, ty = t >> 4;
    const int head = blockIdx.y;
    const int i0 = blockIdx.x * 64;

    const float* Abase = attn + (long)head * SP * SP;
    const float* Vbase = VH + (long)head * SP * 64;

    float acc[4][4] = {};
    for (int k0 = 0; k0 < SP; k0 += 32) {
        __syncthreads();
#pragma unroll
        for (int it = 0; it < 2; ++it) {
            const int idx = t + it * 256;               // 0..511 float4s
            const int r = idx >> 3, c4 = (idx & 7) << 2;    // attn tile 64 x 32
            float4 av = *(const float4*)(Abase + (long)(i0 + r) * SP + k0 + c4);
            As[c4 + 0][r] = av.x; As[c4 + 1][r] = av.y;
            As[c4 + 2][r] = av.z; As[c4 + 3][r] = av.w;
            const int vr = idx >> 4, vc4 = (idx & 15) << 2; // V tile 32 x 64
            float4 vv = *(const float4*)(Vbase + (long)(k0 + vr) * 64 + vc4);
            *(float4*)&Vs[vr][vc4] = vv;
        }
        __syncthreads();
#pragma unroll
        for (int k = 0; k < 32; ++k) {
            float a[4], b[4];
            *(float4*)a = *(const float4*)&As[k][ty * 4];
            *(float4*)b = *(const float4*)&Vs[k][tx * 4];
#pragma unroll
            for (int i = 0; i < 4; ++i)
#pragma unroll
                for (int j = 0; j < 4; ++j)
                    acc[i][j] += a[i] * b[j];
        }
    }

    float* Cbase = CTX + (long)head * SP * 64;
#pragma unroll
    for (int i = 0; i < 4; ++i) {
        float4 o;
        o.x = acc[i][0]; o.y = acc[i][1]; o.z = acc[i][2]; o.w = acc[i][3];
        *(float4*)&Cbase[(long)(i0 + ty * 4 + i) * 64 + tx * 4] = o;
    }
}

// ---------------------------------------------------------------------------
// Residual add + LayerNorm over last dim (1024). One block per row.
// ---------------------------------------------------------------------------
__global__ __launch_bounds__(256) void resln_kernel(
    const float* __restrict__ RES, const float* __restrict__ OUTB,
    const float* __restrict__ gamma, const float* __restrict__ beta,
    float* __restrict__ Y)
{
    __shared__ float red[256];
    const long row = blockIdx.x;
    const int t = threadIdx.x;

    float4 r4 = ((const float4*)(RES  + row * 1024))[t];
    float4 o4 = ((const float4*)(OUTB + row * 1024))[t];
    float x0 = r4.x + o4.x, x1 = r4.y + o4.y, x2 = r4.z + o4.z, x3 = r4.w + o4.w;

    red[t] = x0 + x1 + x2 + x3; __syncthreads();
    for (int s = 128; s > 0; s >>= 1) {
        if (t < s) red[t] += red[t + s];
        __syncthreads();
    }
    const float mu = red[0] * (1.0f / 1024.0f); __syncthreads();

    const float d0 = x0 - mu, d1 = x1 - mu, d2 = x2 - mu, d3 = x3 - mu;
    red[t] = d0 * d0 + d1 * d1 + d2 * d2 + d3 * d3; __syncthreads();
    for (int s = 128; s > 0; s >>= 1) {
        if (t < s) red[t] += red[t + s];
        __syncthreads();
    }
    const float rstd = rsqrtf(red[0] * (1.0f / 1024.0f) + 1e-5f);

    float4 g4 = ((const float4*)gamma)[t];
    float4 b4 = ((const float4*)beta)[t];
    float4 y;
    y.x = d0 * rstd * g4.x + b4.x;
    y.y = d1 * rstd * g4.y + b4.y;
    y.z = d2 * rstd * g4.z + b4.z;
    y.w = d3 * rstd * g4.w + b4.w;
    ((float4*)(Y + row * 1024))[t] = y;
}

// ---------------------------------------------------------------------------
extern "C" void kernel_launch(void* const* d_in, const int* in_sizes, int n_in,
                              void* d_out, int out_size, void* d_ws, size_t ws_size,
                              hipStream_t stream)
{
    const float* k_in  = (const float*)d_in[0];
    const float* v_in  = (const float*)d_in[1];
    const float* q_in  = (const float*)d_in[2];
    const float* Wq    = (const float*)d_in[3];
    const float* bq    = (const float*)d_in[4];
    const float* Wk    = (const float*)d_in[5];
    const float* bk    = (const float*)d_in[6];
    const float* Wv    = (const float*)d_in[7];
    const float* bv    = (const float*)d_in[8];
    const float* Wres  = (const float*)d_in[9];
    const float* bres  = (const float*)d_in[10];
    const float* Wf    = (const float*)d_in[11];
    const float* bf    = (const float*)d_in[12];
    const float* gamma = (const float*)d_in[13];
    const float* beta  = (const float*)d_in[14];

    float* out  = (float*)d_out;                 // [B,S,M] = 8,388,608 floats
    float* attn = out + OUT_ELEMS;               // [64,2048,2048] = 268,435,456 floats

    float* ws  = (float*)d_ws;                   // needs 4 * 32 MB = 128 MB
    float* QH  = ws;
    float* KH  = ws + OUT_ELEMS;
    float* VH  = ws + 2 * OUT_ELEMS;
    float* RES = ws + 3 * OUT_ELEMS;
    float* CTX  = QH;   // QH dead after scores pass
    float* OUTB = KH;   // KH dead after scores pass

    const dim3 blk(256);
    const dim3 ggrid(MD / 128, MROWS / 128);     // (8, 64)

    gemm_bias_128<<<ggrid, blk, 0, stream>>>(q_in, Wq,   bq,   QH,  MROWS, MD, IND);
    gemm_bias_128<<<ggrid, blk, 0, stream>>>(k_in, Wk,   bk,   KH,  MROWS, MD, IND);
    gemm_bias_128<<<ggrid, blk, 0, stream>>>(v_in, Wv,   bv,   VH,  MROWS, MD, IND);
    gemm_bias_128<<<ggrid, blk, 0, stream>>>(q_in, Wres, bres, RES, MROWS, MD, IND);

    const dim3 sgrid(SP / 64, SP / 64, NHEAD);   // (32, 32, 64)
    scores_kernel<<<sgrid, blk, 0, stream>>>(QH, KH, attn, 0.125f);  // 1/sqrt(64)

    softmax_kernel<<<dim3(NHEAD * SP), blk, 0, stream>>>(attn);

    pv_kernel<<<dim3(SP / 64, NHEAD), blk, 0, stream>>>(attn, VH, CTX);

    gemm_bias_128<<<ggrid, blk, 0, stream>>>(CTX, Wf, bf, OUTB, MROWS, MD, MD);

    resln_kernel<<<dim3(MROWS), blk, 0, stream>>>(RES, OUTB, gamma, beta, out);
}